// Round 1
// baseline (898.744 us; speedup 1.0000x reference)
//
#include <hip/hip_runtime.h>

typedef unsigned short u16;
typedef unsigned int u32;
typedef __bf16 bf16_t;
typedef __attribute__((ext_vector_type(8))) bf16_t bf16x8;
typedef __attribute__((ext_vector_type(4))) float f32x4;

__device__ inline u16 f2bf(float f) {
    union { float f; u32 u; } v; v.f = f;
    u32 u = v.u;
    u32 r = (u + 0x7fffu + ((u >> 16) & 1u)) >> 16;
    return (u16)r;
}

// ---------------- fp32 -> bf16 elementwise convert ----------------
__global__ __launch_bounds__(256) void cvt_bf16(const float* __restrict__ in,
                                                u16* __restrict__ out, int n) {
    int i = (blockIdx.x * 256 + threadIdx.x) * 4;
    if (i < n) {
        float4 f = *(const float4*)(in + i);
        ushort4 o;
        o.x = f2bf(f.x); o.y = f2bf(f.y); o.z = f2bf(f.z); o.w = f2bf(f.w);
        *(ushort4*)(out + i) = o;
    }
}

// ---------------- W[K][N] fp32 -> WT[N][K] bf16 ----------------
__global__ __launch_bounds__(256) void transpose_bf16(const float* __restrict__ W,
                                                      u16* __restrict__ WT,
                                                      int K, int N) {
    __shared__ float tile[32][33];
    int tr0 = blockIdx.x * 32;  // K dim
    int tc0 = blockIdx.y * 32;  // N dim
    int t = threadIdx.x;
    for (int i = 0; i < 4; i++) {
        int idx = t + i * 256; int r = idx >> 5, c = idx & 31;
        tile[r][c] = W[(size_t)(tr0 + r) * N + tc0 + c];
    }
    __syncthreads();
    for (int i = 0; i < 4; i++) {
        int idx = t + i * 256; int r = idx >> 5, c = idx & 31;
        WT[(size_t)(tc0 + r) * K + tr0 + c] = f2bf(tile[c][r]);
    }
}

// ---------------- C = A[M][K] * BT[N][K]^T + bias, bf16 in / fp32 acc ----------------
// OUT_T: u16 (bf16 out) or float. TRANS_OUT: store C^T with leading dim ldout.
template <typename OUT_T, bool TRANS_OUT>
__global__ __launch_bounds__(256) void gemm_bt(const u16* __restrict__ A,
                                               const u16* __restrict__ BT,
                                               const float* __restrict__ bias,
                                               OUT_T* __restrict__ C,
                                               int M, int N, int K, int ldout) {
    constexpr int LDSS = 40;  // 32 + 8 pad (keeps 16B fragment contiguity, kills 8-way conflicts)
    __shared__ u16 sA[128 * LDSS];
    __shared__ u16 sB[128 * LDSS];
    int t = threadIdx.x;
    int lane = t & 63, wv = t >> 6;
    int quad = lane >> 4, c16 = lane & 15;
    int bm = blockIdx.x * 128, bn = blockIdx.y * 128;
    int wm = (wv & 1) * 64, wn = (wv >> 1) * 64;
    f32x4 acc[4][4] = {};

    int sr = t >> 2;          // 0..63 : tile row
    int sc = (t & 3) * 8;     // 0/8/16/24 : tile col (elements)
    const u16* Ap = A + (size_t)(bm + sr) * K + sc;
    const u16* Bp = BT + (size_t)(bn + sr) * K + sc;

    for (int k0 = 0; k0 < K; k0 += 32) {
        uint4 a0 = *(const uint4*)(Ap + k0);
        uint4 a1 = *(const uint4*)(Ap + (size_t)64 * K + k0);
        uint4 b0 = *(const uint4*)(Bp + k0);
        uint4 b1 = *(const uint4*)(Bp + (size_t)64 * K + k0);
        __syncthreads();
        *(uint4*)&sA[sr * LDSS + sc] = a0;
        *(uint4*)&sA[(sr + 64) * LDSS + sc] = a1;
        *(uint4*)&sB[sr * LDSS + sc] = b0;
        *(uint4*)&sB[(sr + 64) * LDSS + sc] = b1;
        __syncthreads();
        bf16x8 af[4], bfr[4];
        for (int mi = 0; mi < 4; mi++)
            af[mi] = *(const bf16x8*)&sA[(wm + mi * 16 + c16) * LDSS + quad * 8];
        for (int ni = 0; ni < 4; ni++)
            bfr[ni] = *(const bf16x8*)&sB[(wn + ni * 16 + c16) * LDSS + quad * 8];
        for (int mi = 0; mi < 4; mi++)
            for (int ni = 0; ni < 4; ni++)
                acc[mi][ni] = __builtin_amdgcn_mfma_f32_16x16x32_bf16(
                    af[mi], bfr[ni], acc[mi][ni], 0, 0, 0);
    }

    for (int mi = 0; mi < 4; mi++) {
        for (int ni = 0; ni < 4; ni++) {
            int col = bn + wn + ni * 16 + c16;
            float bv = bias[col];
            for (int p = 0; p < 4; p++) {
                int row = bm + wm + mi * 16 + quad * 4 + p;
                float v = acc[mi][ni][p] + bv;
                size_t off = TRANS_OUT ? ((size_t)col * ldout + row)
                                       : ((size_t)row * ldout + col);
                if constexpr (__is_same(OUT_T, u16)) C[off] = f2bf(v);
                else C[off] = v;
            }
        }
    }
}

// ---------------- flash attention: per block 64 Q-rows of one (b,h); 1 wave = 16 rows ----------------
__global__ __launch_bounds__(256) void mqa_attn(const u16* __restrict__ qh,   // [B*S][2048]
                                                const u16* __restrict__ kh,   // [B*S][128]
                                                const u16* __restrict__ vhT,  // [128][B*S]
                                                u16* __restrict__ outp,       // [B*S][2048]
                                                int S) {
    constexpr float SCALE = 0.08838834764831845f;  // 1/sqrt(128)
    constexpr float LOG2E = 1.4426950408889634f;
    __shared__ u16 sP[4][16 * 40];
    int t = threadIdx.x, lane = t & 63, wv = t >> 6;
    int quad = lane >> 4, c16 = lane & 15;
    int b = blockIdx.z, h = blockIdx.y;
    int q0 = blockIdx.x * 64 + wv * 16;
    int BS = b * S;

    // Q fragments for full Dh=128: A[m=c16][k], 4 chunks of K=32
    const u16* qp = qh + (size_t)(BS + q0 + c16) * 2048 + h * 128 + quad * 8;
    bf16x8 aq[4];
    for (int c = 0; c < 4; c++) aq[c] = *(const bf16x8*)(qp + c * 32);

    f32x4 out[8] = {};
    float mrow[4] = {-1e30f, -1e30f, -1e30f, -1e30f};
    float lrow[4] = {0.f, 0.f, 0.f, 0.f};

    const u16* kbase = kh + (size_t)BS * 128 + quad * 8;
    const u16* vbase = vhT + BS + quad * 8;
    u16* sPw = &sP[wv][0];

    for (int kv0 = 0; kv0 < S; kv0 += 32) {
        // scores: 2 tiles of 16 kv cols, K=128 via 4 MFMAs each
        f32x4 sc2[2] = {};
        for (int hf = 0; hf < 2; hf++) {
            const u16* kp = kbase + (size_t)(kv0 + hf * 16 + c16) * 128;
            for (int c = 0; c < 4; c++) {
                bf16x8 bk = *(const bf16x8*)(kp + c * 32);
                sc2[hf] = __builtin_amdgcn_mfma_f32_16x16x32_bf16(aq[c], bk, sc2[hf], 0, 0, 0);
            }
        }
        // online softmax (rows quad*4+p; reduce across the 16 lanes of this quad-group)
        float al[4];
        for (int p = 0; p < 4; p++) {
            float s0 = sc2[0][p] * SCALE, s1 = sc2[1][p] * SCALE;
            float mx = fmaxf(s0, s1);
            for (int m = 1; m < 16; m <<= 1) mx = fmaxf(mx, __shfl_xor(mx, m, 64));
            float mnew = fmaxf(mrow[p], mx);
            float alpha = exp2f((mrow[p] - mnew) * LOG2E);
            float p0 = exp2f((s0 - mnew) * LOG2E);
            float p1 = exp2f((s1 - mnew) * LOG2E);
            float rs = p0 + p1;
            for (int m = 1; m < 16; m <<= 1) rs += __shfl_xor(rs, m, 64);
            lrow[p] = lrow[p] * alpha + rs;
            mrow[p] = mnew;
            al[p] = alpha;
            sPw[(quad * 4 + p) * 40 + c16] = f2bf(p0);
            sPw[(quad * 4 + p) * 40 + 16 + c16] = f2bf(p1);
        }
        for (int ni = 0; ni < 8; ni++)
            for (int p = 0; p < 4; p++) out[ni][p] *= al[p];
        __syncthreads();
        // P (16x32, A-layout) @ V (32 x 128): read P frag, V frags from vhT (contiguous)
        bf16x8 ap = *(const bf16x8*)&sPw[c16 * 40 + quad * 8];
        for (int ni = 0; ni < 8; ni++) {
            bf16x8 bv = *(const bf16x8*)(vbase + (size_t)(ni * 16 + c16) * 4096 + kv0);
            out[ni] = __builtin_amdgcn_mfma_f32_16x16x32_bf16(ap, bv, out[ni], 0, 0, 0);
        }
        __syncthreads();
    }

    float inv[4];
    for (int p = 0; p < 4; p++) inv[p] = 1.f / lrow[p];
    u16* op = outp + (size_t)(BS + q0 + quad * 4) * 2048 + h * 128;
    for (int ni = 0; ni < 8; ni++)
        for (int p = 0; p < 4; p++)
            op[(size_t)p * 2048 + ni * 16 + c16] = f2bf(out[ni][p] * inv[p]);
}

extern "C" void kernel_launch(void* const* d_in, const int* in_sizes, int n_in,
                              void* d_out, int out_size, void* d_ws, size_t ws_size,
                              hipStream_t stream) {
    const float* q  = (const float*)d_in[0];
    const float* k  = (const float*)d_in[1];
    const float* v  = (const float*)d_in[2];
    const float* Wq = (const float*)d_in[3];
    const float* bq = (const float*)d_in[4];
    const float* Wk = (const float*)d_in[5];
    const float* bk = (const float*)d_in[6];
    const float* Wv = (const float*)d_in[7];
    const float* bv = (const float*)d_in[8];
    const float* Wo = (const float*)d_in[9];
    const float* bo = (const float*)d_in[10];
    float* out = (float*)d_out;

    const int S = 2048, D = 2048, Dh = 128, M = 4096;  // M = B*S
    const int QKV = M * D;       // 8388608
    const int WDD = D * D;       // 4194304
    const int WDH = D * Dh;      // 262144

    u16* ws   = (u16*)d_ws;
    u16* q_bf = ws;
    u16* k_bf = q_bf + QKV;
    u16* v_bf = k_bf + QKV;
    u16* WqT  = v_bf + QKV;
    u16* WoT  = WqT + WDD;
    u16* WkT  = WoT + WDD;
    u16* WvT  = WkT + WDH;
    u16* qhb  = WvT + WDH;       // [M][2048] bf16
    u16* khb  = qhb + QKV;       // [M][128]
    u16* vhTb = khb + M * Dh;    // [128][M]
    u16* aout = vhTb + M * Dh;   // [M][2048]

    cvt_bf16<<<QKV / 1024, 256, 0, stream>>>(q, q_bf, QKV);
    cvt_bf16<<<QKV / 1024, 256, 0, stream>>>(k, k_bf, QKV);
    cvt_bf16<<<QKV / 1024, 256, 0, stream>>>(v, v_bf, QKV);
    transpose_bf16<<<dim3(64, 64), 256, 0, stream>>>(Wq, WqT, D, D);
    transpose_bf16<<<dim3(64, 4), 256, 0, stream>>>(Wk, WkT, D, Dh);
    transpose_bf16<<<dim3(64, 4), 256, 0, stream>>>(Wv, WvT, D, Dh);
    transpose_bf16<<<dim3(64, 64), 256, 0, stream>>>(Wo, WoT, D, D);

    gemm_bt<u16, false><<<dim3(32, 16), 256, 0, stream>>>(q_bf, WqT, bq, qhb, M, D, D, D);
    gemm_bt<u16, false><<<dim3(32, 1), 256, 0, stream>>>(k_bf, WkT, bk, khb, M, Dh, D, Dh);
    gemm_bt<u16, true><<<dim3(32, 1), 256, 0, stream>>>(v_bf, WvT, bv, vhTb, M, Dh, D, M);

    mqa_attn<<<dim3(32, 16, 2), 256, 0, stream>>>(qhb, khb, vhTb, aout, S);

    gemm_bt<float, false><<<dim3(32, 16), 256, 0, stream>>>(aout, WoT, bo, out, M, D, D, D);
}

// Round 2
// 599.183 us; speedup vs baseline: 1.4999x; 1.4999x over previous
//
#include <hip/hip_runtime.h>

typedef unsigned short u16;
typedef unsigned int u32;
typedef __bf16 bf16_t;
typedef __attribute__((ext_vector_type(8))) bf16_t bf16x8;
typedef __attribute__((ext_vector_type(4))) float f32x4;

__device__ inline u16 f2bf(float f) {
    union { float f; u32 u; } v; v.f = f;
    u32 u = v.u;
    u32 r = (u + 0x7fffu + ((u >> 16) & 1u)) >> 16;
    return (u16)r;
}

// ---------------- fp32 -> bf16 elementwise convert ----------------
__global__ __launch_bounds__(256) void cvt_bf16(const float* __restrict__ in,
                                                u16* __restrict__ out, int n) {
    int i = (blockIdx.x * 256 + threadIdx.x) * 4;
    if (i < n) {
        float4 f = *(const float4*)(in + i);
        ushort4 o;
        o.x = f2bf(f.x); o.y = f2bf(f.y); o.z = f2bf(f.z); o.w = f2bf(f.w);
        *(ushort4*)(out + i) = o;
    }
}

// ---------------- W[K][N] fp32 -> WT[N][K] bf16 ----------------
__global__ __launch_bounds__(256) void transpose_bf16(const float* __restrict__ W,
                                                      u16* __restrict__ WT,
                                                      int K, int N) {
    __shared__ float tile[32][33];
    int tr0 = blockIdx.x * 32;  // K dim
    int tc0 = blockIdx.y * 32;  // N dim
    int t = threadIdx.x;
    for (int i = 0; i < 4; i++) {
        int idx = t + i * 256; int r = idx >> 5, c = idx & 31;
        tile[r][c] = W[(size_t)(tr0 + r) * N + tc0 + c];
    }
    __syncthreads();
    for (int i = 0; i < 4; i++) {
        int idx = t + i * 256; int r = idx >> 5, c = idx & 31;
        WT[(size_t)(tc0 + r) * K + tr0 + c] = f2bf(tile[c][r]);
    }
}

// ---------------- C = A[M][K] * BT[N][K]^T + bias, bf16 in / fp32 acc ----------------
template <typename OUT_T, bool TRANS_OUT>
__global__ __launch_bounds__(256) void gemm_bt(const u16* __restrict__ A,
                                               const u16* __restrict__ BT,
                                               const float* __restrict__ bias,
                                               OUT_T* __restrict__ C,
                                               int M, int N, int K, int ldout) {
    constexpr int LDSS = 40;
    __shared__ u16 sA[128 * LDSS];
    __shared__ u16 sB[128 * LDSS];
    int t = threadIdx.x;
    int lane = t & 63, wv = t >> 6;
    int quad = lane >> 4, c16 = lane & 15;
    int bm = blockIdx.x * 128, bn = blockIdx.y * 128;
    int wm = (wv & 1) * 64, wn = (wv >> 1) * 64;
    f32x4 acc[4][4] = {};

    int sr = t >> 2;
    int sc = (t & 3) * 8;
    const u16* Ap = A + (size_t)(bm + sr) * K + sc;
    const u16* Bp = BT + (size_t)(bn + sr) * K + sc;

    for (int k0 = 0; k0 < K; k0 += 32) {
        uint4 a0 = *(const uint4*)(Ap + k0);
        uint4 a1 = *(const uint4*)(Ap + (size_t)64 * K + k0);
        uint4 b0 = *(const uint4*)(Bp + k0);
        uint4 b1 = *(const uint4*)(Bp + (size_t)64 * K + k0);
        __syncthreads();
        *(uint4*)&sA[sr * LDSS + sc] = a0;
        *(uint4*)&sA[(sr + 64) * LDSS + sc] = a1;
        *(uint4*)&sB[sr * LDSS + sc] = b0;
        *(uint4*)&sB[(sr + 64) * LDSS + sc] = b1;
        __syncthreads();
        bf16x8 af[4], bfr[4];
        for (int mi = 0; mi < 4; mi++)
            af[mi] = *(const bf16x8*)&sA[(wm + mi * 16 + c16) * LDSS + quad * 8];
        for (int ni = 0; ni < 4; ni++)
            bfr[ni] = *(const bf16x8*)&sB[(wn + ni * 16 + c16) * LDSS + quad * 8];
        for (int mi = 0; mi < 4; mi++)
            for (int ni = 0; ni < 4; ni++)
                acc[mi][ni] = __builtin_amdgcn_mfma_f32_16x16x32_bf16(
                    af[mi], bfr[ni], acc[mi][ni], 0, 0, 0);
    }

    for (int mi = 0; mi < 4; mi++) {
        for (int ni = 0; ni < 4; ni++) {
            int col = bn + wn + ni * 16 + c16;
            float bv = bias[col];
            for (int p = 0; p < 4; p++) {
                int row = bm + wm + mi * 16 + quad * 4 + p;
                float v = acc[mi][ni][p] + bv;
                size_t off = TRANS_OUT ? ((size_t)col * ldout + row)
                                       : ((size_t)row * ldout + col);
                if constexpr (__is_same(OUT_T, u16)) C[off] = f2bf(v);
                else C[off] = v;
            }
        }
    }
}

// ---------------- flash attention v2 ----------------
// Block: 256 threads = 4 waves, 128 Q rows of one (b,h); wave owns 32 rows (2x16).
// kv tile = 64. K tile + V^T tile staged in LDS (block-shared), P via per-wave LDS.
__global__ __launch_bounds__(256) void mqa_attn(const u16* __restrict__ qh,   // [B*S][2048]
                                                const u16* __restrict__ kh,   // [B*S][128]
                                                const u16* __restrict__ vhT,  // [128][B*S]
                                                u16* __restrict__ outp,       // [B*S][2048]
                                                int S) {
    constexpr float SCALE = 0.08838834764831845f;  // 1/sqrt(128)
    constexpr float LOG2E = 1.4426950408889634f;
    constexpr int KSTR = 136;  // 128 + 8 pad (u16 elems)
    constexpr int VSTR = 72;   // 64 + 8
    constexpr int PSTR = 72;
    __shared__ u16 sK[64 * KSTR];      // 17408 B
    __shared__ u16 sVT[128 * VSTR];    // 18432 B
    __shared__ u16 sP[4 * 32 * PSTR];  // 18432 B

    int t = threadIdx.x, lane = t & 63, wv = t >> 6;
    int quad = lane >> 4, c16 = lane & 15;
    int b = blockIdx.z, h = blockIdx.y;
    int q0 = blockIdx.x * 128 + wv * 32;
    int BS = b * S;

    // Q fragments: rows q0 + mi*16 + c16, k = quad*8 + c*32 over Dh=128
    bf16x8 aq[2][4];
    for (int mi = 0; mi < 2; mi++) {
        const u16* qp = qh + (size_t)(BS + q0 + mi * 16 + c16) * 2048 + h * 128 + quad * 8;
        for (int c = 0; c < 4; c++) aq[mi][c] = *(const bf16x8*)(qp + c * 32);
    }

    f32x4 out[2][8] = {};
    float mrow[2][4] = {{-1e30f, -1e30f, -1e30f, -1e30f}, {-1e30f, -1e30f, -1e30f, -1e30f}};
    float lrow[2][4] = {};

    u16* sPw = sP + wv * 32 * PSTR;

    // staging coords
    int kr = t >> 4, kc = (t & 15) * 8;   // K: 16 rows/pass x 16 lanes
    int vr = t >> 3, vc = (t & 7) * 8;    // VT: 32 rows/pass x 8 lanes
    const u16* kbase = kh + (size_t)(BS + kr) * 128 + kc;
    const u16* vbase = vhT + (size_t)vr * 4096 + BS + vc;

    for (int kv0 = 0; kv0 < S; kv0 += 64) {
        __syncthreads();
        // stage K tile [64][128] and V^T tile [128][64]
        for (int ps = 0; ps < 4; ps++)
            *(uint4*)&sK[(kr + ps * 16) * KSTR + kc] =
                *(const uint4*)(kbase + (size_t)(kv0 + ps * 16) * 128);
        for (int ps = 0; ps < 4; ps++)
            *(uint4*)&sVT[(vr + ps * 32) * VSTR + vc] =
                *(const uint4*)(vbase + (size_t)(ps * 32) * 4096 + kv0);
        __syncthreads();

        // scores: 2 row-tiles x 4 col-tiles, K=128 over 4 chunks
        f32x4 sc[2][4] = {};
        for (int ni = 0; ni < 4; ni++) {
            for (int c = 0; c < 4; c++) {
                bf16x8 bk = *(const bf16x8*)&sK[(ni * 16 + c16) * KSTR + quad * 8 + c * 32];
                sc[0][ni] = __builtin_amdgcn_mfma_f32_16x16x32_bf16(aq[0][c], bk, sc[0][ni], 0, 0, 0);
                sc[1][ni] = __builtin_amdgcn_mfma_f32_16x16x32_bf16(aq[1][c], bk, sc[1][ni], 0, 0, 0);
            }
        }

        // online softmax per row-tile; write P to per-wave LDS
        for (int mi = 0; mi < 2; mi++) {
            float al[4];
            for (int p = 0; p < 4; p++) {
                float s0 = sc[mi][0][p] * SCALE;
                float s1 = sc[mi][1][p] * SCALE;
                float s2 = sc[mi][2][p] * SCALE;
                float s3 = sc[mi][3][p] * SCALE;
                float mx = fmaxf(fmaxf(s0, s1), fmaxf(s2, s3));
                for (int m = 1; m < 16; m <<= 1) mx = fmaxf(mx, __shfl_xor(mx, m, 64));
                float mnew = fmaxf(mrow[mi][p], mx);
                float alpha = exp2f((mrow[mi][p] - mnew) * LOG2E);
                float e0 = exp2f((s0 - mnew) * LOG2E);
                float e1 = exp2f((s1 - mnew) * LOG2E);
                float e2 = exp2f((s2 - mnew) * LOG2E);
                float e3 = exp2f((s3 - mnew) * LOG2E);
                float rs = e0 + e1 + e2 + e3;
                for (int m = 1; m < 16; m <<= 1) rs += __shfl_xor(rs, m, 64);
                lrow[mi][p] = lrow[mi][p] * alpha + rs;
                mrow[mi][p] = mnew;
                al[p] = alpha;
                int row = (mi * 16 + quad * 4 + p) * PSTR;
                sPw[row + c16] = f2bf(e0);
                sPw[row + 16 + c16] = f2bf(e1);
                sPw[row + 32 + c16] = f2bf(e2);
                sPw[row + 48 + c16] = f2bf(e3);
            }
            for (int ni = 0; ni < 8; ni++)
                for (int p = 0; p < 4; p++) out[mi][ni][p] *= al[p];
        }

        // per-wave LDS: ensure P writes landed before reads (no block barrier needed)
        asm volatile("s_waitcnt lgkmcnt(0)" ::: "memory");

        // PV: P[32 x 64] @ V[64 x 128]
        bf16x8 ap[2][2];
        for (int mi = 0; mi < 2; mi++) {
            ap[mi][0] = *(const bf16x8*)&sPw[(mi * 16 + c16) * PSTR + quad * 8];
            ap[mi][1] = *(const bf16x8*)&sPw[(mi * 16 + c16) * PSTR + quad * 8 + 32];
        }
        for (int ni = 0; ni < 8; ni++) {
            bf16x8 bv0 = *(const bf16x8*)&sVT[(ni * 16 + c16) * VSTR + quad * 8];
            bf16x8 bv1 = *(const bf16x8*)&sVT[(ni * 16 + c16) * VSTR + quad * 8 + 32];
            for (int mi = 0; mi < 2; mi++) {
                out[mi][ni] = __builtin_amdgcn_mfma_f32_16x16x32_bf16(ap[mi][0], bv0, out[mi][ni], 0, 0, 0);
                out[mi][ni] = __builtin_amdgcn_mfma_f32_16x16x32_bf16(ap[mi][1], bv1, out[mi][ni], 0, 0, 0);
            }
        }
    }

    // epilogue
    for (int mi = 0; mi < 2; mi++) {
        float inv[4];
        for (int p = 0; p < 4; p++) inv[p] = 1.f / lrow[mi][p];
        u16* op = outp + (size_t)(BS + q0 + mi * 16 + quad * 4) * 2048 + h * 128;
        for (int ni = 0; ni < 8; ni++)
            for (int p = 0; p < 4; p++)
                op[(size_t)p * 2048 + ni * 16 + c16] = f2bf(out[mi][ni][p] * inv[p]);
    }
}

extern "C" void kernel_launch(void* const* d_in, const int* in_sizes, int n_in,
                              void* d_out, int out_size, void* d_ws, size_t ws_size,
                              hipStream_t stream) {
    const float* q  = (const float*)d_in[0];
    const float* k  = (const float*)d_in[1];
    const float* v  = (const float*)d_in[2];
    const float* Wq = (const float*)d_in[3];
    const float* bq = (const float*)d_in[4];
    const float* Wk = (const float*)d_in[5];
    const float* bk = (const float*)d_in[6];
    const float* Wv = (const float*)d_in[7];
    const float* bv = (const float*)d_in[8];
    const float* Wo = (const float*)d_in[9];
    const float* bo = (const float*)d_in[10];
    float* out = (float*)d_out;

    const int S = 2048, D = 2048, Dh = 128, M = 4096;  // M = B*S
    const int QKV = M * D;
    const int WDD = D * D;
    const int WDH = D * Dh;

    u16* ws   = (u16*)d_ws;
    u16* q_bf = ws;
    u16* k_bf = q_bf + QKV;
    u16* v_bf = k_bf + QKV;
    u16* WqT  = v_bf + QKV;
    u16* WoT  = WqT + WDD;
    u16* WkT  = WoT + WDD;
    u16* WvT  = WkT + WDH;
    u16* qhb  = WvT + WDH;       // [M][2048] bf16
    u16* khb  = qhb + QKV;       // [M][128]
    u16* vhTb = khb + M * Dh;    // [128][M]
    u16* aout = vhTb + M * Dh;   // [M][2048]

    cvt_bf16<<<QKV / 1024, 256, 0, stream>>>(q, q_bf, QKV);
    cvt_bf16<<<QKV / 1024, 256, 0, stream>>>(k, k_bf, QKV);
    cvt_bf16<<<QKV / 1024, 256, 0, stream>>>(v, v_bf, QKV);
    transpose_bf16<<<dim3(64, 64), 256, 0, stream>>>(Wq, WqT, D, D);
    transpose_bf16<<<dim3(64, 4), 256, 0, stream>>>(Wk, WkT, D, Dh);
    transpose_bf16<<<dim3(64, 4), 256, 0, stream>>>(Wv, WvT, D, Dh);
    transpose_bf16<<<dim3(64, 64), 256, 0, stream>>>(Wo, WoT, D, D);

    gemm_bt<u16, false><<<dim3(32, 16), 256, 0, stream>>>(q_bf, WqT, bq, qhb, M, D, D, D);
    gemm_bt<u16, false><<<dim3(32, 1), 256, 0, stream>>>(k_bf, WkT, bk, khb, M, Dh, D, Dh);
    gemm_bt<u16, true><<<dim3(32, 1), 256, 0, stream>>>(v_bf, WvT, bv, vhTb, M, Dh, D, M);

    mqa_attn<<<dim3(16, 16, 2), 256, 0, stream>>>(qhb, khb, vhTb, aout, S);

    gemm_bt<float, false><<<dim3(32, 16), 256, 0, stream>>>(aout, WoT, bo, out, M, D, D, D);
}

// Round 3
// 463.817 us; speedup vs baseline: 1.9377x; 1.2919x over previous
//
#include <hip/hip_runtime.h>

typedef unsigned short u16;
typedef unsigned int u32;
typedef __bf16 bf16_t;
typedef __attribute__((ext_vector_type(8))) bf16_t bf16x8;
typedef __attribute__((ext_vector_type(4))) float f32x4;

__device__ inline u16 f2bf(float f) {
    union { float f; u32 u; } v; v.f = f;
    u32 u = v.u;
    u32 r = (u + 0x7fffu + ((u >> 16) & 1u)) >> 16;
    return (u16)r;
}

// async global->LDS, 16B per lane; LDS dest is wave-uniform base + lane*16
__device__ inline void async_cp16(const void* g, void* l) {
    __builtin_amdgcn_global_load_lds((const __attribute__((address_space(1))) void*)g,
                                     (__attribute__((address_space(3))) void*)l, 16, 0, 0);
}

// ---------------- fp32 -> bf16 convert, 3 arrays fused ----------------
__global__ __launch_bounds__(256) void cvt3(const float* __restrict__ a,
                                            const float* __restrict__ b,
                                            const float* __restrict__ c,
                                            u16* __restrict__ oa, u16* __restrict__ ob,
                                            u16* __restrict__ oc) {
    int z = blockIdx.y;
    const float* in = z == 0 ? a : (z == 1 ? b : c);
    u16* out = z == 0 ? oa : (z == 1 ? ob : oc);
    int i = (blockIdx.x * 256 + threadIdx.x) * 4;
    float4 f = *(const float4*)(in + i);
    ushort4 o;
    o.x = f2bf(f.x); o.y = f2bf(f.y); o.z = f2bf(f.z); o.w = f2bf(f.w);
    *(ushort4*)(out + i) = o;
}

// ---------------- W[K][N] fp32 -> WT[N][K] bf16, 2 matrices fused ----------------
__global__ __launch_bounds__(256) void transpose2(const float* __restrict__ W0,
                                                  u16* __restrict__ T0,
                                                  const float* __restrict__ W1,
                                                  u16* __restrict__ T1,
                                                  int K, int N) {
    const float* W = blockIdx.z == 0 ? W0 : W1;
    u16* WT = blockIdx.z == 0 ? T0 : T1;
    __shared__ float tile[32][33];
    int tr0 = blockIdx.x * 32;
    int tc0 = blockIdx.y * 32;
    int t = threadIdx.x;
    for (int i = 0; i < 4; i++) {
        int idx = t + i * 256; int r = idx >> 5, c = idx & 31;
        tile[r][c] = W[(size_t)(tr0 + r) * N + tc0 + c];
    }
    __syncthreads();
    for (int i = 0; i < 4; i++) {
        int idx = t + i * 256; int r = idx >> 5, c = idx & 31;
        WT[(size_t)(tc0 + r) * K + tr0 + c] = f2bf(tile[c][r]);
    }
}

// ---------------- C = A[M][K] * BT[N][K]^T + bias, m97-pattern staging ----------------
template <typename OUT_T, bool TRANS_OUT>
__global__ __launch_bounds__(256) void gemm_bt(const u16* __restrict__ A,
                                               const u16* __restrict__ BT,
                                               const float* __restrict__ bias,
                                               OUT_T* __restrict__ C,
                                               int M, int N, int K, int ldout) {
    __shared__ u16 sA[128 * 32];
    __shared__ u16 sB[128 * 32];
    int t = threadIdx.x, lane = t & 63, wv = t >> 6;
    int quad = lane >> 4, c16 = lane & 15;
    int bm = blockIdx.x * 128, bn = blockIdx.y * 128;
    int wm = (wv & 1) * 64, wn = (wv >> 1) * 64;
    f32x4 acc[4][4] = {};

    // wave wv stages rows [wv*32, wv*32+32); lane -> row wv*32 + (lane>>2), 16B chunk lane&3
    int srow = wv * 32 + (lane >> 2);
    int scol = (lane & 3) * 8;
    const u16* Ag = A + (size_t)(bm + srow) * K + scol;
    const u16* Bg = BT + (size_t)(bn + srow) * K + scol;
    u16* sAd = &sA[(wv * 32) * 32];
    u16* sBd = &sB[(wv * 32) * 32];

    for (int k0 = 0; k0 < K; k0 += 32) {
        __syncthreads();
        async_cp16(Ag + k0, sAd);
        async_cp16(Ag + (size_t)16 * K + k0, sAd + 16 * 32);
        async_cp16(Bg + k0, sBd);
        async_cp16(Bg + (size_t)16 * K + k0, sBd + 16 * 32);
        __syncthreads();  // compiler drains vmcnt(0) here
        bf16x8 af[4], bfr[4];
        for (int mi = 0; mi < 4; mi++)
            af[mi] = *(const bf16x8*)&sA[(wm + mi * 16 + c16) * 32 + quad * 8];
        for (int ni = 0; ni < 4; ni++)
            bfr[ni] = *(const bf16x8*)&sB[(wn + ni * 16 + c16) * 32 + quad * 8];
        for (int mi = 0; mi < 4; mi++)
            for (int ni = 0; ni < 4; ni++)
                acc[mi][ni] = __builtin_amdgcn_mfma_f32_16x16x32_bf16(
                    af[mi], bfr[ni], acc[mi][ni], 0, 0, 0);
    }

    for (int mi = 0; mi < 4; mi++) {
        for (int ni = 0; ni < 4; ni++) {
            int col = bn + wn + ni * 16 + c16;
            float bv = bias[col];
            for (int p = 0; p < 4; p++) {
                int row = bm + wm + mi * 16 + quad * 4 + p;
                float v = acc[mi][ni][p] + bv;
                size_t off = TRANS_OUT ? ((size_t)col * ldout + row)
                                       : ((size_t)row * ldout + col);
                if constexpr (__is_same(OUT_T, u16)) C[off] = f2bf(v);
                else C[off] = v;
            }
        }
    }
}

// ---------------- fused K/V projection: blockIdx.y selects K (normal) or V (transposed out) ----
__global__ __launch_bounds__(256) void gemm_kv(const u16* __restrict__ kbf,
                                               const u16* __restrict__ vbf,
                                               const u16* __restrict__ WkT,
                                               const u16* __restrict__ WvT,
                                               const float* __restrict__ bkp,
                                               const float* __restrict__ bvp,
                                               u16* __restrict__ khb,
                                               u16* __restrict__ vhT,
                                               int K, int Mld) {
    bool isv = blockIdx.y == 1;
    const u16* A = isv ? vbf : kbf;
    const u16* BT = isv ? WvT : WkT;
    const float* bias = isv ? bvp : bkp;
    __shared__ u16 sA[128 * 32];
    __shared__ u16 sB[128 * 32];
    int t = threadIdx.x, lane = t & 63, wv = t >> 6;
    int quad = lane >> 4, c16 = lane & 15;
    int bm = blockIdx.x * 128;
    int wm = (wv & 1) * 64, wn = (wv >> 1) * 64;
    f32x4 acc[4][4] = {};

    int srow = wv * 32 + (lane >> 2);
    int scol = (lane & 3) * 8;
    const u16* Ag = A + (size_t)(bm + srow) * K + scol;
    const u16* Bg = BT + (size_t)srow * K + scol;
    u16* sAd = &sA[(wv * 32) * 32];
    u16* sBd = &sB[(wv * 32) * 32];

    for (int k0 = 0; k0 < K; k0 += 32) {
        __syncthreads();
        async_cp16(Ag + k0, sAd);
        async_cp16(Ag + (size_t)16 * K + k0, sAd + 16 * 32);
        async_cp16(Bg + k0, sBd);
        async_cp16(Bg + (size_t)16 * K + k0, sBd + 16 * 32);
        __syncthreads();
        bf16x8 af[4], bfr[4];
        for (int mi = 0; mi < 4; mi++)
            af[mi] = *(const bf16x8*)&sA[(wm + mi * 16 + c16) * 32 + quad * 8];
        for (int ni = 0; ni < 4; ni++)
            bfr[ni] = *(const bf16x8*)&sB[(wn + ni * 16 + c16) * 32 + quad * 8];
        for (int mi = 0; mi < 4; mi++)
            for (int ni = 0; ni < 4; ni++)
                acc[mi][ni] = __builtin_amdgcn_mfma_f32_16x16x32_bf16(
                    af[mi], bfr[ni], acc[mi][ni], 0, 0, 0);
    }

    for (int mi = 0; mi < 4; mi++) {
        for (int ni = 0; ni < 4; ni++) {
            int col = wn + ni * 16 + c16;
            float bv = bias[col];
            for (int p = 0; p < 4; p++) {
                int row = bm + wm + mi * 16 + quad * 4 + p;
                float v = acc[mi][ni][p] + bv;
                if (isv) vhT[(size_t)col * Mld + row] = f2bf(v);
                else khb[(size_t)row * 128 + col] = f2bf(v);
            }
        }
    }
}

// ---------------- flash attention v3: transposed scores, static softmax ----------------
// Block: 4 waves, 128 Q rows of one (b,h); wave owns 32 rows (mi=0,1 x 16). kv tile = 64.
// S^T = K*Q^T puts all kv-scores of a q-row in one lane -> no in-loop shuffles, packed P writes.
__global__ __launch_bounds__(256) void mqa_attn(const u16* __restrict__ qh,   // [B*S][2048]
                                                const u16* __restrict__ kh,   // [B*S][128]
                                                const u16* __restrict__ vhT,  // [128][B*S]
                                                u16* __restrict__ outp,       // [B*S][2048]
                                                int S) {
    constexpr float CEXP = 0.08838834764831845f * 1.4426950408889634f;  // scale * log2(e)
    constexpr int KSTR = 136;  // u16 elems
    constexpr int VSTR = 72;
    constexpr int PSTR = 72;
    __shared__ u16 sK[64 * KSTR];          // 17408 B
    __shared__ u16 sVT[128 * VSTR];        // 18432 B
    __shared__ u16 sP[4 * 2 * 16 * PSTR];  // 18432 B

    int t = threadIdx.x, lane = t & 63, wv = t >> 6;
    int quad = lane >> 4, c16 = lane & 15;
    int b = blockIdx.z, h = blockIdx.y;
    int q0 = blockIdx.x * 128 + wv * 32;
    int BS = b * S;

    // Q fragments (B-operand of S^T mfma): rows q0 + mi*16 + c16, k contiguous
    bf16x8 aq[2][4];
    for (int mi = 0; mi < 2; mi++) {
        const u16* qp = qh + (size_t)(BS + q0 + mi * 16 + c16) * 2048 + h * 128 + quad * 8;
        for (int c = 0; c < 4; c++) aq[mi][c] = *(const bf16x8*)(qp + c * 32);
    }

    f32x4 out[2][8] = {};
    f32x4 lsumv[2] = {};

    u16* sPw = sP + wv * (2 * 16 * PSTR);

    int kr = t >> 4, kc = (t & 15) * 8;
    int vr = t >> 3, vc = (t & 7) * 8;
    const u16* kbase = kh + (size_t)(BS + kr) * 128 + kc;
    const u16* vbase = vhT + (size_t)vr * 4096 + BS + vc;

    for (int kv0 = 0; kv0 < S; kv0 += 64) {
        __syncthreads();
        for (int ps = 0; ps < 4; ps++)
            *(uint4*)&sK[(kr + ps * 16) * KSTR + kc] =
                *(const uint4*)(kbase + (size_t)(kv0 + ps * 16) * 128);
        for (int ps = 0; ps < 4; ps++)
            *(uint4*)&sVT[(vr + ps * 32) * VSTR + vc] =
                *(const uint4*)(vbase + (size_t)(ps * 32) * 4096 + kv0);
        __syncthreads();

        // S^T tile: rows = kv (64), cols = q (32). mfma(K-frag, Q-frag): D row=kv, col=q.
        f32x4 sc[2][4] = {};
        for (int ni = 0; ni < 4; ni++) {
            for (int c = 0; c < 4; c++) {
                bf16x8 bk = *(const bf16x8*)&sK[(ni * 16 + c16) * KSTR + quad * 8 + c * 32];
                sc[0][ni] = __builtin_amdgcn_mfma_f32_16x16x32_bf16(bk, aq[0][c], sc[0][ni], 0, 0, 0);
                sc[1][ni] = __builtin_amdgcn_mfma_f32_16x16x32_bf16(bk, aq[1][c], sc[1][ni], 0, 0, 0);
            }
        }

        // static softmax: lane (c16,quad) holds q=c16, kv=ni*16+quad*4+p
        // l summed from truncated bf16 values so truncation bias cancels in PV/l
        for (int mi = 0; mi < 2; mi++) {
            u16* sProw = sPw + mi * (16 * PSTR) + c16 * PSTR;
            for (int ni = 0; ni < 4; ni++) {
                u32 eu[4];
                f32x4 et;
                for (int p = 0; p < 4; p++) {
                    float e = __builtin_amdgcn_exp2f(sc[mi][ni][p] * CEXP);
                    union { float f; u32 u; } cv; cv.f = e;
                    eu[p] = cv.u;
                    cv.u &= 0xffff0000u;
                    et[p] = cv.f;
                }
                lsumv[mi] += et;
                u32 pk0 = __builtin_amdgcn_perm(eu[1], eu[0], 0x07060302u);
                u32 pk1 = __builtin_amdgcn_perm(eu[3], eu[2], 0x07060302u);
                *(uint2*)&sProw[ni * 16 + quad * 4] = make_uint2(pk0, pk1);
            }
        }
        asm volatile("s_waitcnt lgkmcnt(0)" ::: "memory");

        // PV: O = P[32 x 64] * V[64 x 128]; A-frag of P: row q=c16, kv contiguous
        bf16x8 ap[2][2];
        for (int mi = 0; mi < 2; mi++) {
            ap[mi][0] = *(const bf16x8*)&sPw[mi * (16 * PSTR) + c16 * PSTR + quad * 8];
            ap[mi][1] = *(const bf16x8*)&sPw[mi * (16 * PSTR) + c16 * PSTR + quad * 8 + 32];
        }
        for (int ni = 0; ni < 8; ni++) {
            bf16x8 bv0 = *(const bf16x8*)&sVT[(ni * 16 + c16) * VSTR + quad * 8];
            bf16x8 bv1 = *(const bf16x8*)&sVT[(ni * 16 + c16) * VSTR + quad * 8 + 32];
            for (int mi = 0; mi < 2; mi++) {
                out[mi][ni] = __builtin_amdgcn_mfma_f32_16x16x32_bf16(ap[mi][0], bv0, out[mi][ni], 0, 0, 0);
                out[mi][ni] = __builtin_amdgcn_mfma_f32_16x16x32_bf16(ap[mi][1], bv1, out[mi][ni], 0, 0, 0);
            }
        }
    }

    // epilogue: reduce l across quads, redistribute by q-row, scale, store
    for (int mi = 0; mi < 2; mi++) {
        float lp = lsumv[mi][0] + lsumv[mi][1] + lsumv[mi][2] + lsumv[mi][3];
        lp += __shfl_xor(lp, 16, 64);
        lp += __shfl_xor(lp, 32, 64);  // now every lane holds l(q = c16) of this mi
        float inv[4];
        for (int p = 0; p < 4; p++)
            inv[p] = 1.f / __shfl(lp, quad * 4 + p, 64);  // l for q-row quad*4+p
        u16* op = outp + (size_t)(BS + q0 + mi * 16 + quad * 4) * 2048 + h * 128;
        for (int ni = 0; ni < 8; ni++)
            for (int p = 0; p < 4; p++)
                op[(size_t)p * 2048 + ni * 16 + c16] = f2bf(out[mi][ni][p] * inv[p]);
    }
}

extern "C" void kernel_launch(void* const* d_in, const int* in_sizes, int n_in,
                              void* d_out, int out_size, void* d_ws, size_t ws_size,
                              hipStream_t stream) {
    const float* q  = (const float*)d_in[0];
    const float* k  = (const float*)d_in[1];
    const float* v  = (const float*)d_in[2];
    const float* Wq = (const float*)d_in[3];
    const float* bq = (const float*)d_in[4];
    const float* Wk = (const float*)d_in[5];
    const float* bk = (const float*)d_in[6];
    const float* Wv = (const float*)d_in[7];
    const float* bv = (const float*)d_in[8];
    const float* Wo = (const float*)d_in[9];
    const float* bo = (const float*)d_in[10];
    float* out = (float*)d_out;

    const int S = 2048, D = 2048, Dh = 128, M = 4096;  // M = B*S
    const int QKV = M * D;
    const int WDD = D * D;
    const int WDH = D * Dh;

    u16* ws   = (u16*)d_ws;
    u16* q_bf = ws;
    u16* k_bf = q_bf + QKV;
    u16* v_bf = k_bf + QKV;
    u16* WqT  = v_bf + QKV;
    u16* WoT  = WqT + WDD;
    u16* WkT  = WoT + WDD;
    u16* WvT  = WkT + WDH;
    u16* qhb  = WvT + WDH;       // [M][2048] bf16
    u16* khb  = qhb + QKV;       // [M][128]
    u16* vhTb = khb + M * Dh;    // [128][M]
    u16* aout = vhTb + M * Dh;   // [M][2048]

    cvt3<<<dim3(QKV / 1024, 3), 256, 0, stream>>>(q, k, v, q_bf, k_bf, v_bf);
    transpose2<<<dim3(64, 64, 2), 256, 0, stream>>>(Wq, WqT, Wo, WoT, D, D);
    transpose2<<<dim3(64, 4, 2), 256, 0, stream>>>(Wk, WkT, Wv, WvT, D, Dh);

    gemm_bt<u16, false><<<dim3(32, 16), 256, 0, stream>>>(q_bf, WqT, bq, qhb, M, D, D, D);
    gemm_kv<<<dim3(32, 2), 256, 0, stream>>>(k_bf, v_bf, WkT, WvT, bk, bv, khb, vhTb, D, M);

    mqa_attn<<<dim3(16, 16, 2), 256, 0, stream>>>(qhb, khb, vhTb, aout, S);

    gemm_bt<float, false><<<dim3(32, 16), 256, 0, stream>>>(aout, WoT, bo, out, M, D, D, D);
}